// Round 3
// baseline (2148.405 us; speedup 1.0000x reference)
//
#include <hip/hip_runtime.h>

#define NPTS 4096

// ---------------- head fold (fp32, post-selection) ----------------
__global__ void fold_head_k(const float* __restrict__ hw, const float* __restrict__ hb,
                            const float* __restrict__ hg, const float* __restrict__ hbt,
                            const float* __restrict__ hm, const float* __restrict__ hv,
                            int O, int C, float* __restrict__ hwf, float* __restrict__ cb) {
  int t = blockIdx.x * 256 + threadIdx.x;
  if (t >= O * C) return;
  int o = t / C, c = t - o * C;
  float A = hg[o] * (1.0f / sqrtf(hv[o] + 1e-5f));
  hwf[t] = A * hw[t];
  if (c == 0) cb[o] = (hb[o] - hm[o]) * A + hbt[o];
}

// ---------------- per-channel BN constants in fp64 ----------------
__global__ void fold_edge_f64(const float* __restrict__ g, const float* __restrict__ bt,
                              const float* __restrict__ m, const float* __restrict__ v,
                              int O, double* __restrict__ Ad, double* __restrict__ c0) {
  int o = blockIdx.x * 64 + threadIdx.x;
  if (o >= O) return;
  double A = (double)g[o] / sqrt((double)v[o] + (double)1e-5f);
  Ad[o] = A;
  c0[o] = (double)bt[o] - (double)m[o] * A;
}

// ---------------- squared norms, fp64 accumulate ----------------
__global__ void sq_f64(const float* __restrict__ X, int lda, int C,
                       double* __restrict__ sq, int nrows) {
  int r = blockIdx.x * 256 + threadIdx.x;
  if (r >= nrows) return;
  const float* p = X + (size_t)r * lda;
  double s = 0.0;
  for (int c = 0; c < C; ++c) { double xv = p[c]; s += xv * xv; }
  sq[r] = s;
}

// ---------------- layer-1 (C=3) raw dots in fp64 ----------------
__global__ void pq3_raw(const float* __restrict__ x, const float* __restrict__ w,
                        double* __restrict__ Pw, double* __restrict__ Qw) {
  int t = blockIdx.x * 256 + threadIdx.x;  // B*N*64 threads
  int r = t >> 6, o = t & 63;
  double x0 = x[r * 3], x1 = x[r * 3 + 1], x2 = x[r * 3 + 2];
  const float* wr = w + o * 6;
  Pw[(size_t)r * 64 + o] = x0 * (double)wr[0] + x1 * (double)wr[1] + x2 * (double)wr[2];
  Qw[(size_t)r * 64 + o] = x0 * (double)wr[3] + x1 * (double)wr[4] + x2 * (double)wr[5];
}

// finish: Q = A*(Qw - Pw) + c0 ; P = A*Pw   (in place, fp64)
__global__ void pq_finish(double* __restrict__ P, double* __restrict__ Q,
                          const double* __restrict__ Ad, const double* __restrict__ c0,
                          int omask, int total) {
  int t = blockIdx.x * 256 + threadIdx.x;
  if (t >= total) return;
  int o = t & omask;
  double pw = P[t], qw = Q[t], A = Ad[o];
  Q[t] = A * (qw - pw) + c0[o];
  P[t] = A * pw;
}

// ---------------- layer-1 distances (C=3) in fp64 ----------------
__global__ void dist3_f64(const float* __restrict__ xb, const double* __restrict__ sqb,
                          double* __restrict__ D, int r0) {
  int t = blockIdx.x * 256 + threadIdx.x;  // rows_tile * NPTS threads
  int rl = t >> 12;
  int mc = t & (NPTS - 1);
  int n = r0 + rl;
  double ax = xb[n * 3], ay = xb[n * 3 + 1], az = xb[n * 3 + 2];
  double bx = xb[mc * 3], by = xb[mc * 3 + 1], bz = xb[mc * 3 + 2];
  double inner = ax * bx + ay * by + az * bz;
  D[(size_t)rl * NPTS + mc] = 2.0 * inner - sqb[n] - sqb[mc];
}

// ---------------- fp32-in / fp64-accumulate GEMM: Out = A(MxC) @ B(NxC)^T ----------------
// EPI: 0 = raw dot, 2 = 2*acc - sqA[row] - sqB[col]
template <int EPI>
__global__ __launch_bounds__(256) void gemm_nt_f64(
    const float* __restrict__ A, int lda,
    const float* __restrict__ Bm, int ldb,
    double* __restrict__ Out, int ldo, int C,
    const double* __restrict__ sqA, const double* __restrict__ sqB) {
  __shared__ __align__(16) float As[16][68];
  __shared__ __align__(16) float Bs[16][68];
  const int tx = threadIdx.x, ty = threadIdx.y;  // 16x16
  const int tid = ty * 16 + tx;
  const int row0 = blockIdx.y * 64, col0 = blockIdx.x * 64;
  const int lr = tid >> 2;
  const int lc = (tid & 3) << 2;
  const float* Ap = A + (size_t)(row0 + lr) * lda + lc;
  const float* Bp = Bm + (size_t)(col0 + lr) * ldb + lc;
  double acc[4][4] = {};
  for (int c0 = 0; c0 < C; c0 += 16) {
    float4 av = *(const float4*)(Ap + c0);
    float4 bv = *(const float4*)(Bp + c0);
    As[lc + 0][lr] = av.x; As[lc + 1][lr] = av.y;
    As[lc + 2][lr] = av.z; As[lc + 3][lr] = av.w;
    Bs[lc + 0][lr] = bv.x; Bs[lc + 1][lr] = bv.y;
    Bs[lc + 2][lr] = bv.z; Bs[lc + 3][lr] = bv.w;
    __syncthreads();
#pragma unroll
    for (int c = 0; c < 16; ++c) {
      float4 a4 = *(const float4*)(&As[c][ty << 2]);
      float4 b4 = *(const float4*)(&Bs[c][tx << 2]);
      double aa[4] = {(double)a4.x, (double)a4.y, (double)a4.z, (double)a4.w};
      double bb[4] = {(double)b4.x, (double)b4.y, (double)b4.z, (double)b4.w};
#pragma unroll
      for (int i = 0; i < 4; ++i)
#pragma unroll
        for (int j = 0; j < 4; ++j) acc[i][j] = fma(aa[i], bb[j], acc[i][j]);
    }
    __syncthreads();
  }
  const int row = row0 + (ty << 2), col = col0 + (tx << 2);
#pragma unroll
  for (int i = 0; i < 4; ++i)
#pragma unroll
    for (int j = 0; j < 4; ++j) {
      double va = acc[i][j];
      if (EPI == 2) va = 2.0 * va - sqA[row + i] - sqB[col + j];
      Out[(size_t)(row + i) * ldo + col + j] = va;
    }
}

// ---------------- top-20 + gather + leakyrelu + max over k (fp64 selection) ----------------
__global__ __launch_bounds__(256) void topk_max_f64(
    const double* __restrict__ D,  // rows_tile x NPTS
    const double* __restrict__ P, const double* __restrict__ Q,
    float* __restrict__ Y, int ldy, int O, int bBase, int r0) {
  const int tid = threadIdx.x;
  const int nloc = blockIdx.x;
  const int n = r0 + nloc;
  const double* drow = D + (size_t)nloc * NPTS;
  double v[16];
#pragma unroll
  for (int j = 0; j < 16; ++j) v[j] = drow[j * 256 + tid];

  __shared__ double sv[4];
  __shared__ int sm[4];
  __shared__ int selm[20];

  for (int it = 0; it < 20; ++it) {
    double bvv = v[0];
    int bj = 0;
#pragma unroll
    for (int j = 1; j < 16; ++j)
      if (v[j] > bvv) { bvv = v[j]; bj = j; }
    int bm = bj * 256 + tid;
#pragma unroll
    for (int off = 32; off > 0; off >>= 1) {
      double ov = __shfl_down(bvv, off);
      int om = __shfl_down(bm, off);
      if (ov > bvv || (ov == bvv && om < bm)) { bvv = ov; bm = om; }
    }
    if ((tid & 63) == 0) { sv[tid >> 6] = bvv; sm[tid >> 6] = bm; }
    __syncthreads();
    if (tid == 0) {
      double fv = sv[0]; int fm = sm[0];
      for (int wv = 1; wv < 4; ++wv)
        if (sv[wv] > fv || (sv[wv] == fv && sm[wv] < fm)) { fv = sv[wv]; fm = sm[wv]; }
      selm[it] = fm;
    }
    __syncthreads();
    int fm = selm[it];
    if ((fm & 255) == tid) v[fm >> 8] = -1.0e300;
  }
  __syncthreads();

  const double LEAK = (double)0.2f;
  for (int o = tid; o < O; o += 256) {
    double q = Q[(size_t)(bBase + n) * O + o];
    double best = -1.0e300;
#pragma unroll
    for (int k = 0; k < 20; ++k) {
      double t = P[(size_t)(bBase + selm[k]) * O + o] + q;
      t = t > 0.0 ? t : LEAK * t;
      best = fmax(best, t);
    }
    Y[(size_t)(bBase + n) * ldy + o] = (float)best;
  }
}

// ---------------- fp32 head GEMM: Out = relu(A @ B^T + bias) ----------------
__global__ __launch_bounds__(256) void gemm_head(
    const float* __restrict__ A, int lda,
    const float* __restrict__ Bm, int ldb,
    float* __restrict__ Out, int ldo, int C,
    const float* __restrict__ bias) {
  __shared__ __align__(16) float As[16][68];
  __shared__ __align__(16) float Bs[16][68];
  const int tx = threadIdx.x, ty = threadIdx.y;
  const int tid = ty * 16 + tx;
  const int row0 = blockIdx.y * 64, col0 = blockIdx.x * 64;
  const int lr = tid >> 2;
  const int lc = (tid & 3) << 2;
  const float* Ap = A + (size_t)(row0 + lr) * lda + lc;
  const float* Bp = Bm + (size_t)(col0 + lr) * ldb + lc;
  float acc[4][4] = {};
  for (int c0 = 0; c0 < C; c0 += 16) {
    float4 av = *(const float4*)(Ap + c0);
    float4 bv = *(const float4*)(Bp + c0);
    As[lc + 0][lr] = av.x; As[lc + 1][lr] = av.y;
    As[lc + 2][lr] = av.z; As[lc + 3][lr] = av.w;
    Bs[lc + 0][lr] = bv.x; Bs[lc + 1][lr] = bv.y;
    Bs[lc + 2][lr] = bv.z; Bs[lc + 3][lr] = bv.w;
    __syncthreads();
#pragma unroll
    for (int c = 0; c < 16; ++c) {
      float4 a4 = *(const float4*)(&As[c][ty << 2]);
      float4 b4 = *(const float4*)(&Bs[c][tx << 2]);
      float aa[4] = {a4.x, a4.y, a4.z, a4.w};
      float bb[4] = {b4.x, b4.y, b4.z, b4.w};
#pragma unroll
      for (int i = 0; i < 4; ++i)
#pragma unroll
        for (int j = 0; j < 4; ++j) acc[i][j] = fmaf(aa[i], bb[j], acc[i][j]);
    }
    __syncthreads();
  }
  const int row = row0 + (ty << 2), col = col0 + (tx << 2);
#pragma unroll
  for (int i = 0; i < 4; ++i) {
    float vals[4];
#pragma unroll
    for (int j = 0; j < 4; ++j) {
      float t = acc[i][j] + bias[col + j];
      vals[j] = t > 0.f ? t : 0.f;
    }
    *(float4*)(&Out[(size_t)(row + i) * ldo + col]) =
        make_float4(vals[0], vals[1], vals[2], vals[3]);
  }
}

// ---------------- final 128->1 dot ----------------
__global__ void final_dot_k(const float* __restrict__ h2, const float* __restrict__ w3,
                            const float* __restrict__ b3, float* __restrict__ out) {
  int gt = blockIdx.x * 256 + threadIdx.x;
  int row = gt >> 6, lane = gt & 63;
  float s = h2[(size_t)row * 128 + lane] * w3[lane] +
            h2[(size_t)row * 128 + 64 + lane] * w3[64 + lane];
#pragma unroll
  for (int off = 32; off > 0; off >>= 1) s += __shfl_down(s, off);
  if (lane == 0) out[row] = s + b3[0];
}

extern "C" void kernel_launch(void* const* d_in, const int* in_sizes, int n_in,
                              void* d_out, int out_size, void* d_ws, size_t ws_size,
                              hipStream_t stream) {
  const int B = 2, N = NPTS;
  const float* x = (const float*)d_in[0];
  const float* w[4]  = {(const float*)d_in[1], (const float*)d_in[6],
                        (const float*)d_in[11], (const float*)d_in[16]};
  const float* g[4]  = {(const float*)d_in[2], (const float*)d_in[7],
                        (const float*)d_in[12], (const float*)d_in[17]};
  const float* bt[4] = {(const float*)d_in[3], (const float*)d_in[8],
                        (const float*)d_in[13], (const float*)d_in[18]};
  const float* mm[4] = {(const float*)d_in[4], (const float*)d_in[9],
                        (const float*)d_in[14], (const float*)d_in[19]};
  const float* vv[4] = {(const float*)d_in[5], (const float*)d_in[10],
                        (const float*)d_in[15], (const float*)d_in[20]};
  const float* hw1 = (const float*)d_in[21]; const float* hb1 = (const float*)d_in[22];
  const float* hg1 = (const float*)d_in[23]; const float* hbt1 = (const float*)d_in[24];
  const float* hm1 = (const float*)d_in[25]; const float* hv1 = (const float*)d_in[26];
  const float* hw2 = (const float*)d_in[27]; const float* hb2 = (const float*)d_in[28];
  const float* hg2 = (const float*)d_in[29]; const float* hbt2 = (const float*)d_in[30];
  const float* hm2 = (const float*)d_in[31]; const float* hv2 = (const float*)d_in[32];
  const float* hw3 = (const float*)d_in[33]; const float* hb3 = (const float*)d_in[34];
  float* out = (float*)d_out;

  char* wsb = (char*)d_ws;
  size_t off = 0;
  auto alloc = [&](size_t nbytes) {
    char* p = wsb + off;
    off += (nbytes + 255) & ~(size_t)255;
    return p;
  };
  float*  xc   = (float*)alloc((size_t)B * N * 512 * 4);
  double* Pd   = (double*)alloc((size_t)B * N * 256 * 8);
  double* Qd   = (double*)alloc((size_t)B * N * 256 * 8);
  double* sq   = (double*)alloc((size_t)B * N * 8);
  double* Ad   = (double*)alloc(256 * 8);
  double* c0   = (double*)alloc(256 * 8);
  float*  hwf1 = (float*)alloc(256 * 512 * 4);
  float*  cb1  = (float*)alloc(256 * 4);
  float*  hwf2 = (float*)alloc(128 * 256 * 4);
  float*  cb2  = (float*)alloc(128 * 4);
  double* D    = (double*)(wsb + off);
  size_t avail = (ws_size > off) ? (ws_size - off) : 0;
  int rows_tile = 4096;
  while ((size_t)rows_tile * N * 8 > avail && rows_tile > 64) rows_tile >>= 1;

  // dims = [(3,64), (64,64), (64,128), (128,256)]  -- layer L input = x_{L} output
  const int Cin[4]  = {3, 64, 64, 128};     // FIXED: was {3,64,128,256}
  const int Oc[4]   = {64, 64, 128, 256};
  const int ioff[4] = {0, 0, 64, 128};
  const int ooff[4] = {0, 64, 128, 256};
  dim3 blk2(16, 16);

  for (int L = 0; L < 4; ++L) {
    const int C = Cin[L], O = Oc[L];
    const float* in = (L == 0) ? x : (xc + ioff[L]);
    const int lda = (L == 0) ? 3 : 512;

    fold_edge_f64<<<dim3((O + 63) / 64), dim3(64), 0, stream>>>(
        g[L], bt[L], mm[L], vv[L], O, Ad, c0);
    sq_f64<<<dim3((B * N + 255) / 256), dim3(256), 0, stream>>>(in, lda, C, sq, B * N);
    if (L == 0) {
      pq3_raw<<<dim3(B * N * 64 / 256), dim3(256), 0, stream>>>(x, w[0], Pd, Qd);
    } else {
      // raw dots from UNROUNDED input weights: Pw = x . w_d, Qw = x . w_c
      gemm_nt_f64<0><<<dim3(O / 64, B * N / 64), blk2, 0, stream>>>(
          in, lda, w[L], 2 * C, Pd, O, C, nullptr, nullptr);
      gemm_nt_f64<0><<<dim3(O / 64, B * N / 64), blk2, 0, stream>>>(
          in, lda, w[L] + C, 2 * C, Qd, O, C, nullptr, nullptr);
    }
    pq_finish<<<dim3(B * N * O / 256), dim3(256), 0, stream>>>(
        Pd, Qd, Ad, c0, O - 1, B * N * O);
    for (int b = 0; b < B; ++b) {
      for (int r0 = 0; r0 < N; r0 += rows_tile) {
        if (L == 0) {
          dist3_f64<<<dim3((unsigned)((size_t)rows_tile * N / 256)), dim3(256), 0, stream>>>(
              x + (size_t)b * N * 3, sq + b * N, D, r0);
        } else {
          gemm_nt_f64<2><<<dim3(N / 64, rows_tile / 64), blk2, 0, stream>>>(
              in + ((size_t)b * N + r0) * lda, lda, in + (size_t)b * N * lda, lda,
              D, N, C, sq + b * N + r0, sq + b * N);
        }
        topk_max_f64<<<dim3(rows_tile), dim3(256), 0, stream>>>(
            D, Pd, Qd, xc + ooff[L], 512, O, b * N, r0);
      }
    }
  }

  fold_head_k<<<dim3((256 * 512 + 255) / 256), dim3(256), 0, stream>>>(
      hw1, hb1, hg1, hbt1, hm1, hv1, 256, 512, hwf1, cb1);
  fold_head_k<<<dim3((128 * 256 + 255) / 256), dim3(256), 0, stream>>>(
      hw2, hb2, hg2, hbt2, hm2, hv2, 128, 256, hwf2, cb2);

  float* h1 = (float*)Pd;
  float* h2 = (float*)Qd;
  gemm_head<<<dim3(256 / 64, B * N / 64), blk2, 0, stream>>>(
      xc, 512, hwf1, 512, h1, 256, 512, cb1);
  gemm_head<<<dim3(128 / 64, B * N / 64), blk2, 0, stream>>>(
      h1, 256, hwf2, 256, h2, 128, 256, cb2);
  final_dot_k<<<dim3(B * N / 4), dim3(256), 0, stream>>>(h2, hw3, hb3, out);
}

// Round 4
// 1431.164 us; speedup vs baseline: 1.5012x; 1.5012x over previous
//
#include <hip/hip_runtime.h>

#define NPTS 4096
#define EPSF 1e-5f

// ---------------- fold kernels (BN affine folded into weights) ----------------
__global__ void fold_edge_k(const float* __restrict__ w, const float* __restrict__ g,
                            const float* __restrict__ bt, const float* __restrict__ m,
                            const float* __restrict__ v, int O, int C,
                            float* __restrict__ wdf, float* __restrict__ wqf,
                            float* __restrict__ c0) {
  int t = blockIdx.x * 256 + threadIdx.x;
  if (t >= O * C) return;
  int o = t / C, c = t - o * C;
  float A = g[o] * (1.0f / sqrtf(v[o] + EPSF));
  float wd = w[o * 2 * C + c], wc = w[o * 2 * C + C + c];
  wdf[t] = A * wd;
  wqf[t] = A * (wc - wd);
  if (c == 0) c0[o] = bt[o] - m[o] * A;
}

__global__ void fold_head_k(const float* __restrict__ hw, const float* __restrict__ hb,
                            const float* __restrict__ hg, const float* __restrict__ hbt,
                            const float* __restrict__ hm, const float* __restrict__ hv,
                            int O, int C, float* __restrict__ hwf, float* __restrict__ cb) {
  int t = blockIdx.x * 256 + threadIdx.x;
  if (t >= O * C) return;
  int o = t / C, c = t - o * C;
  float A = hg[o] * (1.0f / sqrtf(hv[o] + EPSF));
  hwf[t] = A * hw[t];
  if (c == 0) cb[o] = (hb[o] - hm[o]) * A + hbt[o];
}

// ---------------- squared norms ----------------
__global__ void sq_k(const float* __restrict__ X, int lda, int C,
                     float* __restrict__ sq, int nrows) {
  int r = blockIdx.x * 256 + threadIdx.x;
  if (r >= nrows) return;
  const float* p = X + (size_t)r * lda;
  float s = 0.f;
  for (int c = 0; c < C; ++c) s += p[c] * p[c];
  sq[r] = s;
}

// ---------------- layer-1 (C=3) special kernels ----------------
__global__ void pq3_k(const float* __restrict__ x, const float* __restrict__ wdf,
                      const float* __restrict__ wqf, const float* __restrict__ c0,
                      float* __restrict__ P, float* __restrict__ Q) {
  int t = blockIdx.x * 256 + threadIdx.x;  // B*N*64 threads
  int r = t >> 6, o = t & 63;
  float x0 = x[r * 3], x1 = x[r * 3 + 1], x2 = x[r * 3 + 2];
  P[(size_t)r * 64 + o] = x0 * wdf[o * 3] + x1 * wdf[o * 3 + 1] + x2 * wdf[o * 3 + 2];
  Q[(size_t)r * 64 + o] = x0 * wqf[o * 3] + x1 * wqf[o * 3 + 1] + x2 * wqf[o * 3 + 2] + c0[o];
}

__global__ void dist3_k(const float* __restrict__ xb, const float* __restrict__ sqb,
                        float* __restrict__ D, int r0) {
  int t = blockIdx.x * 256 + threadIdx.x;  // rows_tile * NPTS threads
  int rl = t >> 12;
  int mc = t & (NPTS - 1);
  int n = r0 + rl;
  float x0 = xb[n * 3], x1 = xb[n * 3 + 1], x2 = xb[n * 3 + 2];
  float y0 = xb[mc * 3], y1 = xb[mc * 3 + 1], y2 = xb[mc * 3 + 2];
  float inner = x0 * y0 + x1 * y1 + x2 * y2;
  D[(size_t)rl * NPTS + mc] = 2.0f * inner - sqb[n] - sqb[mc];
}

// ---------------- generic fp32 GEMM: Out = A(MxC,lda) @ B(NxC,ldb)^T ----------------
// EPI: 0 = none (P), 1 = +bias[col] (Q), 2 = 2*acc - sqA[row] - sqB[col] (neg dist),
//      3 = relu(acc + bias[col]) (head)
template <int EPI>
__global__ __launch_bounds__(256) void gemm_nt(
    const float* __restrict__ A, int lda,
    const float* __restrict__ Bm, int ldb,
    float* __restrict__ Out, int ldo, int C,
    const float* __restrict__ sqA, const float* __restrict__ sqB,
    const float* __restrict__ bias) {
  __shared__ __align__(16) float As[16][68];
  __shared__ __align__(16) float Bs[16][68];
  const int tx = threadIdx.x, ty = threadIdx.y;  // 16x16
  const int tid = ty * 16 + tx;
  const int row0 = blockIdx.y * 64, col0 = blockIdx.x * 64;
  const int lr = tid >> 2;          // 0..63 tile row
  const int lc = (tid & 3) << 2;    // 0,4,8,12 c-offset
  const float* Ap = A + (size_t)(row0 + lr) * lda + lc;
  const float* Bp = Bm + (size_t)(col0 + lr) * ldb + lc;
  float acc[4][4] = {};
  for (int c0 = 0; c0 < C; c0 += 16) {
    float4 av = *(const float4*)(Ap + c0);
    float4 bv = *(const float4*)(Bp + c0);
    As[lc + 0][lr] = av.x; As[lc + 1][lr] = av.y;
    As[lc + 2][lr] = av.z; As[lc + 3][lr] = av.w;
    Bs[lc + 0][lr] = bv.x; Bs[lc + 1][lr] = bv.y;
    Bs[lc + 2][lr] = bv.z; Bs[lc + 3][lr] = bv.w;
    __syncthreads();
#pragma unroll
    for (int c = 0; c < 16; ++c) {
      float4 a4 = *(const float4*)(&As[c][ty << 2]);
      float4 b4 = *(const float4*)(&Bs[c][tx << 2]);
      float aa[4] = {a4.x, a4.y, a4.z, a4.w};
      float bb[4] = {b4.x, b4.y, b4.z, b4.w};
#pragma unroll
      for (int i = 0; i < 4; ++i)
#pragma unroll
        for (int j = 0; j < 4; ++j) acc[i][j] = fmaf(aa[i], bb[j], acc[i][j]);
    }
    __syncthreads();
  }
  const int row = row0 + (ty << 2), col = col0 + (tx << 2);
#pragma unroll
  for (int i = 0; i < 4; ++i) {
    float vals[4];
#pragma unroll
    for (int j = 0; j < 4; ++j) {
      float va = acc[i][j];
      if (EPI == 0) vals[j] = va;
      else if (EPI == 1) vals[j] = va + bias[col + j];
      else if (EPI == 2) vals[j] = 2.0f * va - sqA[row + i] - sqB[col + j];
      else { float t = va + bias[col + j]; vals[j] = t > 0.f ? t : 0.f; }
    }
    *(float4*)(&Out[(size_t)(row + i) * ldo + col]) =
        make_float4(vals[0], vals[1], vals[2], vals[3]);
  }
}

// ---------------- top-20 + gather + leakyrelu + max over k ----------------
// one block (256 thr = 4 waves) per point. Phase 1: each wave selects its
// local top-20 of 1024 values (barrier-free, shfl_xor butterflies).
// Phase 2: wave 0 merges the 4x20 candidates. Tie-break = smaller index,
// matching lax.top_k; max-pool is order-invariant so only the SET matters.
__global__ __launch_bounds__(256) void topk_max_f32(
    const float* __restrict__ D,   // rows_tile x NPTS (row-local)
    const float* __restrict__ P,   // (B*N, O)
    const float* __restrict__ Q,   // (B*N, O)
    float* __restrict__ Y,         // xc + layer offset, row stride ldy
    int ldy, int O, int bBase, int r0) {
  const int tid = threadIdx.x;
  const int lane = tid & 63, wid = tid >> 6;
  const int nloc = blockIdx.x;
  const int n = r0 + nloc;
  const float* drow = D + (size_t)nloc * NPTS + wid * 1024;
  float v[16];
#pragma unroll
  for (int j = 0; j < 16; ++j) v[j] = drow[j * 64 + lane];

  __shared__ float cv[80];
  __shared__ int   cm[80];
  __shared__ int   selm[20];

  // phase 1: per-wave top-20 (no barriers)
  for (int it = 0; it < 20; ++it) {
    float bv = v[0]; int bj = 0;
#pragma unroll
    for (int j = 1; j < 16; ++j)
      if (v[j] > bv) { bv = v[j]; bj = j; }
    int bm = wid * 1024 + bj * 64 + lane;
#pragma unroll
    for (int off = 1; off < 64; off <<= 1) {
      float ov = __shfl_xor(bv, off);
      int om = __shfl_xor(bm, off);
      if (ov > bv || (ov == bv && om < bm)) { bv = ov; bm = om; }
    }
    if (lane == 0) { cv[wid * 20 + it] = bv; cm[wid * 20 + it] = bm; }
    // winner slot owner clears its copy
    if ((bm & 63) == lane) v[(bm >> 6) & 15] = -3.0e38f;
  }
  __syncthreads();

  // phase 2: wave 0 merges 80 candidates (slots 0..79)
  if (wid == 0) {
    float c0 = cv[lane];
    int   m0 = cm[lane];
    float c1 = (lane < 16) ? cv[64 + lane] : -3.0e38f;
    int   m1 = (lane < 16) ? cm[64 + lane] : 0x7fffffff;
    for (int it = 0; it < 20; ++it) {
      float bv; int bm, bs;
      if (c0 > c1 || (c0 == c1 && m0 < m1)) { bv = c0; bm = m0; bs = lane; }
      else { bv = c1; bm = m1; bs = 64 + lane; }
#pragma unroll
      for (int off = 1; off < 64; off <<= 1) {
        float ov = __shfl_xor(bv, off);
        int om = __shfl_xor(bm, off);
        int os = __shfl_xor(bs, off);
        if (ov > bv || (ov == bv && om < bm)) { bv = ov; bm = om; bs = os; }
      }
      if (lane == 0) selm[it] = bm;
      if (bs == lane) c0 = -3.0e38f;
      else if (bs == 64 + lane) c1 = -3.0e38f;
    }
  }
  __syncthreads();

  int sel[20];
#pragma unroll
  for (int k = 0; k < 20; ++k) sel[k] = selm[k];

  for (int o = tid; o < O; o += 256) {
    float q = Q[(size_t)(bBase + n) * O + o];
    float best = -3.0e38f;
#pragma unroll
    for (int k = 0; k < 20; ++k) {
      float t = P[(size_t)(bBase + sel[k]) * O + o] + q;
      t = t > 0.f ? t : 0.2f * t;
      best = fmaxf(best, t);
    }
    Y[(size_t)(bBase + n) * ldy + o] = best;
  }
}

// ---------------- final 128->1 dot ----------------
__global__ void final_dot_k(const float* __restrict__ h2, const float* __restrict__ w3,
                            const float* __restrict__ b3, float* __restrict__ out) {
  int gt = blockIdx.x * 256 + threadIdx.x;
  int row = gt >> 6, lane = gt & 63;
  float s = h2[(size_t)row * 128 + lane] * w3[lane] +
            h2[(size_t)row * 128 + 64 + lane] * w3[64 + lane];
#pragma unroll
  for (int off = 32; off > 0; off >>= 1) s += __shfl_down(s, off);
  if (lane == 0) out[row] = s + b3[0];
}

extern "C" void kernel_launch(void* const* d_in, const int* in_sizes, int n_in,
                              void* d_out, int out_size, void* d_ws, size_t ws_size,
                              hipStream_t stream) {
  const int B = 2, N = NPTS;
  const float* x = (const float*)d_in[0];
  const float* w[4]  = {(const float*)d_in[1], (const float*)d_in[6],
                        (const float*)d_in[11], (const float*)d_in[16]};
  const float* g[4]  = {(const float*)d_in[2], (const float*)d_in[7],
                        (const float*)d_in[12], (const float*)d_in[17]};
  const float* bt[4] = {(const float*)d_in[3], (const float*)d_in[8],
                        (const float*)d_in[13], (const float*)d_in[18]};
  const float* mm[4] = {(const float*)d_in[4], (const float*)d_in[9],
                        (const float*)d_in[14], (const float*)d_in[19]};
  const float* vv[4] = {(const float*)d_in[5], (const float*)d_in[10],
                        (const float*)d_in[15], (const float*)d_in[20]};
  const float* hw1 = (const float*)d_in[21]; const float* hb1 = (const float*)d_in[22];
  const float* hg1 = (const float*)d_in[23]; const float* hbt1 = (const float*)d_in[24];
  const float* hm1 = (const float*)d_in[25]; const float* hv1 = (const float*)d_in[26];
  const float* hw2 = (const float*)d_in[27]; const float* hb2 = (const float*)d_in[28];
  const float* hg2 = (const float*)d_in[29]; const float* hbt2 = (const float*)d_in[30];
  const float* hm2 = (const float*)d_in[31]; const float* hv2 = (const float*)d_in[32];
  const float* hw3 = (const float*)d_in[33]; const float* hb3 = (const float*)d_in[34];
  float* out = (float*)d_out;

  char* wsb = (char*)d_ws;
  size_t off = 0;
  auto alloc = [&](size_t nbytes) {
    char* p = wsb + off;
    off += (nbytes + 255) & ~(size_t)255;
    return p;
  };
  float* xc   = (float*)alloc((size_t)B * N * 512 * 4);
  float* P    = (float*)alloc((size_t)B * N * 256 * 4);
  float* Q    = (float*)alloc((size_t)B * N * 256 * 4);
  float* sq   = (float*)alloc((size_t)B * N * 4);
  float* wdf  = (float*)alloc(256 * 256 * 4);
  float* wqf  = (float*)alloc(256 * 256 * 4);
  float* c0   = (float*)alloc(256 * 4);
  float* hwf1 = (float*)alloc(256 * 512 * 4);
  float* cb1  = (float*)alloc(256 * 4);
  float* hwf2 = (float*)alloc(128 * 256 * 4);
  float* cb2  = (float*)alloc(128 * 4);
  float* D    = (float*)(wsb + off);
  size_t avail = (ws_size > off) ? (ws_size - off) : 0;
  int rows_tile = 4096;
  while ((size_t)rows_tile * N * 4 > avail && rows_tile > 64) rows_tile >>= 1;

  // dims = [(3,64), (64,64), (64,128), (128,256)]
  const int Cin[4]  = {3, 64, 64, 128};
  const int Oc[4]   = {64, 64, 128, 256};
  const int ioff[4] = {0, 0, 64, 128};
  const int ooff[4] = {0, 64, 128, 256};
  dim3 blk2(16, 16);

  for (int L = 0; L < 4; ++L) {
    const int C = Cin[L], O = Oc[L];
    const float* in = (L == 0) ? x : (xc + ioff[L]);
    const int lda = (L == 0) ? 3 : 512;

    fold_edge_k<<<dim3((O * C + 255) / 256), dim3(256), 0, stream>>>(
        w[L], g[L], bt[L], mm[L], vv[L], O, C, wdf, wqf, c0);
    sq_k<<<dim3((B * N + 255) / 256), dim3(256), 0, stream>>>(in, lda, C, sq, B * N);
    if (L == 0) {
      pq3_k<<<dim3(B * N * 64 / 256), dim3(256), 0, stream>>>(x, wdf, wqf, c0, P, Q);
    } else {
      gemm_nt<0><<<dim3(O / 64, B * N / 64), blk2, 0, stream>>>(
          in, lda, wdf, C, P, O, C, nullptr, nullptr, nullptr);
      gemm_nt<1><<<dim3(O / 64, B * N / 64), blk2, 0, stream>>>(
          in, lda, wqf, C, Q, O, C, nullptr, nullptr, c0);
    }
    for (int b = 0; b < B; ++b) {
      for (int r0 = 0; r0 < N; r0 += rows_tile) {
        if (L == 0) {
          dist3_k<<<dim3((unsigned)((size_t)rows_tile * N / 256)), dim3(256), 0, stream>>>(
              x + (size_t)b * N * 3, sq + b * N, D, r0);
        } else {
          gemm_nt<2><<<dim3(N / 64, rows_tile / 64), blk2, 0, stream>>>(
              in + ((size_t)b * N + r0) * lda, lda, in + (size_t)b * N * lda, lda,
              D, N, C, sq + b * N + r0, sq + b * N, nullptr);
        }
        topk_max_f32<<<dim3(rows_tile), dim3(256), 0, stream>>>(
            D, P, Q, xc + ooff[L], 512, O, b * N, r0);
      }
    }
  }

  fold_head_k<<<dim3((256 * 512 + 255) / 256), dim3(256), 0, stream>>>(
      hw1, hb1, hg1, hbt1, hm1, hv1, 256, 512, hwf1, cb1);
  fold_head_k<<<dim3((128 * 256 + 255) / 256), dim3(256), 0, stream>>>(
      hw2, hb2, hg2, hbt2, hm2, hv2, 128, 256, hwf2, cb2);

  float* h1 = P;
  float* h2 = Q;
  gemm_nt<3><<<dim3(256 / 64, B * N / 64), blk2, 0, stream>>>(
      xc, 512, hwf1, 512, h1, 256, 512, nullptr, nullptr, cb1);
  gemm_nt<3><<<dim3(128 / 64, B * N / 64), blk2, 0, stream>>>(
      h1, 256, hwf2, 256, h2, 128, 256, nullptr, nullptr, cb2);
  final_dot_k<<<dim3(B * N / 4), dim3(256), 0, stream>>>(h2, hw3, hb3, out);
}

// Round 5
// 837.172 us; speedup vs baseline: 2.5663x; 1.7095x over previous
//
#include <hip/hip_runtime.h>

#define NPTS 4096
#define EPSF 1e-5f

// ---------------- sortable-key helpers ----------------
__device__ __forceinline__ unsigned f2u(float f) {
  unsigned b = __float_as_uint(f);
  return (b & 0x80000000u) ? ~b : (b | 0x80000000u);
}
__device__ __forceinline__ float u2f(unsigned u) {
  unsigned b = (u & 0x80000000u) ? (u & 0x7fffffffu) : ~u;
  return __uint_as_float(b);
}
__device__ __forceinline__ unsigned shflx(unsigned v, int j) {
  return (unsigned)__shfl_xor((int)v, j);
}
__device__ __forceinline__ unsigned long long shflx64(unsigned long long v, int j) {
  unsigned lo = (unsigned)__shfl_xor((int)(unsigned)(v & 0xffffffffull), j);
  unsigned hi = (unsigned)__shfl_xor((int)(unsigned)(v >> 32), j);
  return ((unsigned long long)hi << 32) | lo;
}

// ascending bitonic sort of 64 u32 keys (1/lane)
__device__ __forceinline__ unsigned sort64_u32(unsigned v, int lane) {
#pragma unroll
  for (int k = 2; k <= 64; k <<= 1) {
#pragma unroll
    for (int j = k >> 1; j >= 1; j >>= 1) {
      unsigned ov = shflx(v, j);
      bool kmin = ((lane & j) == 0) == ((lane & k) == 0);
      v = kmin ? (v < ov ? v : ov) : (v > ov ? v : ov);
    }
  }
  return v;
}

// ascending bitonic sort of 128 u32 keys (2/lane: a=elem[lane], b=elem[64+lane])
__device__ __forceinline__ void sort128_u32(unsigned& a, unsigned& b, int lane) {
#pragma unroll
  for (int k = 2; k <= 128; k <<= 1) {
#pragma unroll
    for (int j = k >> 1; j >= 1; j >>= 1) {
      if (j == 64) {  // k==128 only: in-lane CE, ascending
        unsigned mn = a < b ? a : b, mx = a < b ? b : a;
        a = mn; b = mx;
      } else {
        unsigned oa = shflx(a, j), ob = shflx(b, j);
        bool lower = (lane & j) == 0;
        bool asca, ascb;
        if (k == 128) { asca = true; ascb = true; }
        else if (k == 64) { asca = true; ascb = false; }
        else { asca = ((lane & k) == 0); ascb = asca; }
        a = (lower == asca) ? (a < oa ? a : oa) : (a > oa ? a : oa);
        b = (lower == ascb) ? (b < ob ? b : ob) : (b > ob ? b : ob);
      }
    }
  }
}

// ascending bitonic sort of 64 u64 keys (1/lane)
__device__ __forceinline__ unsigned long long sort64_u64(unsigned long long v, int lane) {
#pragma unroll
  for (int k = 2; k <= 64; k <<= 1) {
#pragma unroll
    for (int j = k >> 1; j >= 1; j >>= 1) {
      unsigned long long ov = shflx64(v, j);
      bool kmin = ((lane & j) == 0) == ((lane & k) == 0);
      v = kmin ? (v < ov ? v : ov) : (v > ov ? v : ov);
    }
  }
  return v;
}

// ascending bitonic sort of 128 u64 keys (2/lane)
__device__ __forceinline__ void sort128_u64(unsigned long long& a, unsigned long long& b,
                                            int lane) {
#pragma unroll
  for (int k = 2; k <= 128; k <<= 1) {
#pragma unroll
    for (int j = k >> 1; j >= 1; j >>= 1) {
      if (j == 64) {
        unsigned long long mn = a < b ? a : b, mx = a < b ? b : a;
        a = mn; b = mx;
      } else {
        unsigned long long oa = shflx64(a, j), ob = shflx64(b, j);
        bool lower = (lane & j) == 0;
        bool asca, ascb;
        if (k == 128) { asca = true; ascb = true; }
        else if (k == 64) { asca = true; ascb = false; }
        else { asca = ((lane & k) == 0); ascb = asca; }
        a = (lower == asca) ? (a < oa ? a : oa) : (a > oa ? a : oa);
        b = (lower == ascb) ? (b < ob ? b : ob) : (b > ob ? b : ob);
      }
    }
  }
}

// ---------------- fold kernels (BN affine folded into weights) ----------------
__global__ void fold_edge_k(const float* __restrict__ w, const float* __restrict__ g,
                            const float* __restrict__ bt, const float* __restrict__ m,
                            const float* __restrict__ v, int O, int C,
                            float* __restrict__ wdf, float* __restrict__ wqf,
                            float* __restrict__ c0) {
  int t = blockIdx.x * 256 + threadIdx.x;
  if (t >= O * C) return;
  int o = t / C, c = t - o * C;
  float A = g[o] * (1.0f / sqrtf(v[o] + EPSF));
  float wd = w[o * 2 * C + c], wc = w[o * 2 * C + C + c];
  wdf[t] = A * wd;
  wqf[t] = A * (wc - wd);
  if (c == 0) c0[o] = bt[o] - m[o] * A;
}

__global__ void fold_head_k(const float* __restrict__ hw, const float* __restrict__ hb,
                            const float* __restrict__ hg, const float* __restrict__ hbt,
                            const float* __restrict__ hm, const float* __restrict__ hv,
                            int O, int C, float* __restrict__ hwf, float* __restrict__ cb) {
  int t = blockIdx.x * 256 + threadIdx.x;
  if (t >= O * C) return;
  int o = t / C, c = t - o * C;
  float A = hg[o] * (1.0f / sqrtf(hv[o] + EPSF));
  hwf[t] = A * hw[t];
  if (c == 0) cb[o] = (hb[o] - hm[o]) * A + hbt[o];
}

// ---------------- squared norms ----------------
__global__ void sq_k(const float* __restrict__ X, int lda, int C,
                     float* __restrict__ sq, int nrows) {
  int r = blockIdx.x * 256 + threadIdx.x;
  if (r >= nrows) return;
  const float* p = X + (size_t)r * lda;
  float s = 0.f;
  for (int c = 0; c < C; ++c) s += p[c] * p[c];
  sq[r] = s;
}

// ---------------- layer-1 (C=3) special kernels ----------------
__global__ void pq3_k(const float* __restrict__ x, const float* __restrict__ wdf,
                      const float* __restrict__ wqf, const float* __restrict__ c0,
                      float* __restrict__ P, float* __restrict__ Q) {
  int t = blockIdx.x * 256 + threadIdx.x;  // B*N*64 threads
  int r = t >> 6, o = t & 63;
  float x0 = x[r * 3], x1 = x[r * 3 + 1], x2 = x[r * 3 + 2];
  P[(size_t)r * 64 + o] = x0 * wdf[o * 3] + x1 * wdf[o * 3 + 1] + x2 * wdf[o * 3 + 2];
  Q[(size_t)r * 64 + o] = x0 * wqf[o * 3] + x1 * wqf[o * 3 + 1] + x2 * wqf[o * 3 + 2] + c0[o];
}

__global__ void dist3_k(const float* __restrict__ xb, const float* __restrict__ sqb,
                        float* __restrict__ D, int r0) {
  int t = blockIdx.x * 256 + threadIdx.x;  // rows_tile * NPTS threads
  int rl = t >> 12;
  int mc = t & (NPTS - 1);
  int n = r0 + rl;
  float x0 = xb[n * 3], x1 = xb[n * 3 + 1], x2 = xb[n * 3 + 2];
  float y0 = xb[mc * 3], y1 = xb[mc * 3 + 1], y2 = xb[mc * 3 + 2];
  float inner = x0 * y0 + x1 * y1 + x2 * y2;
  D[(size_t)rl * NPTS + mc] = 2.0f * inner - sqb[n] - sqb[mc];
}

// ---------------- generic fp32 GEMM: Out = A(MxC,lda) @ B(NxC,ldb)^T ----------------
template <int EPI>
__global__ __launch_bounds__(256) void gemm_nt(
    const float* __restrict__ A, int lda,
    const float* __restrict__ Bm, int ldb,
    float* __restrict__ Out, int ldo, int C,
    const float* __restrict__ sqA, const float* __restrict__ sqB,
    const float* __restrict__ bias) {
  __shared__ __align__(16) float As[16][68];
  __shared__ __align__(16) float Bs[16][68];
  const int tx = threadIdx.x, ty = threadIdx.y;  // 16x16
  const int tid = ty * 16 + tx;
  const int row0 = blockIdx.y * 64, col0 = blockIdx.x * 64;
  const int lr = tid >> 2;
  const int lc = (tid & 3) << 2;
  const float* Ap = A + (size_t)(row0 + lr) * lda + lc;
  const float* Bp = Bm + (size_t)(col0 + lr) * ldb + lc;
  float acc[4][4] = {};
  for (int c0 = 0; c0 < C; c0 += 16) {
    float4 av = *(const float4*)(Ap + c0);
    float4 bv = *(const float4*)(Bp + c0);
    As[lc + 0][lr] = av.x; As[lc + 1][lr] = av.y;
    As[lc + 2][lr] = av.z; As[lc + 3][lr] = av.w;
    Bs[lc + 0][lr] = bv.x; Bs[lc + 1][lr] = bv.y;
    Bs[lc + 2][lr] = bv.z; Bs[lc + 3][lr] = bv.w;
    __syncthreads();
#pragma unroll
    for (int c = 0; c < 16; ++c) {
      float4 a4 = *(const float4*)(&As[c][ty << 2]);
      float4 b4 = *(const float4*)(&Bs[c][tx << 2]);
      float aa[4] = {a4.x, a4.y, a4.z, a4.w};
      float bb[4] = {b4.x, b4.y, b4.z, b4.w};
#pragma unroll
      for (int i = 0; i < 4; ++i)
#pragma unroll
        for (int j = 0; j < 4; ++j) acc[i][j] = fmaf(aa[i], bb[j], acc[i][j]);
    }
    __syncthreads();
  }
  const int row = row0 + (ty << 2), col = col0 + (tx << 2);
#pragma unroll
  for (int i = 0; i < 4; ++i) {
    float vals[4];
#pragma unroll
    for (int j = 0; j < 4; ++j) {
      float va = acc[i][j];
      if (EPI == 0) vals[j] = va;
      else if (EPI == 1) vals[j] = va + bias[col + j];
      else if (EPI == 2) vals[j] = 2.0f * va - sqA[row + i] - sqB[col + j];
      else { float t = va + bias[col + j]; vals[j] = t > 0.f ? t : 0.f; }
    }
    *(float4*)(&Out[(size_t)(row + i) * ldo + col]) =
        make_float4(vals[0], vals[1], vals[2], vals[3]);
  }
}

// ---------------- top-20 via threshold filter + bitonic sort ----------------
// One block (256 thr = 4 waves) per point. Value i lives at thread (i&255),
// register (i>>8). T0 = exact 20th-largest per-thread max (lower bound on the
// 20th-largest value); filter v>=T0 (provably >=20, expected ~25 candidates);
// exact top-20 = sort on key (f2u(v)<<32)|~idx  (value desc, index asc =
// lax.top_k tie semantics). Fallback to iterative extraction if >128 cands.
__global__ __launch_bounds__(256) void topk_max_f32(
    const float* __restrict__ D,   // rows_tile x NPTS (row-local)
    const float* __restrict__ P,   // (B*N, O)
    const float* __restrict__ Q,   // (B*N, O)
    float* __restrict__ Y,         // xc + layer offset, row stride ldy
    int ldy, int O, int bBase, int r0) {
  const int tid = threadIdx.x;
  const int lane = tid & 63, wid = tid >> 6;
  const int nloc = blockIdx.x;
  const int n = r0 + nloc;
  const float* drow = D + (size_t)nloc * NPTS;

  __shared__ unsigned wv[80];
  __shared__ unsigned ck[128];
  __shared__ int      ci[128];
  __shared__ int      cnt_s;
  __shared__ int      selm[20];
  __shared__ float    part[4 * 256];
  __shared__ float    fcv[80];
  __shared__ int      fcm[80];

  float v[16];
#pragma unroll
  for (int j = 0; j < 16; ++j) v[j] = drow[j * 256 + tid];

  // A: per-thread max
  float M = v[0];
#pragma unroll
  for (int j = 1; j < 16; ++j) M = fmaxf(M, v[j]);

  // B: per-wave ascending sort of the 64 per-lane maxima (values only)
  unsigned mk = sort64_u32(f2u(M), lane);

  if (tid == 0) cnt_s = 0;
  // C: wave's top-20 maxima (lanes 44..63 after ascending sort) -> LDS
  if (lane >= 44) wv[wid * 20 + (63 - lane)] = mk;
  __syncthreads();

  // D: all waves sort the 80-union (padded to 128 with 0 = -inf key);
  //    20th largest = ascending position 108 = reg b of lane 44.
  unsigned a0 = wv[lane];
  unsigned b0 = (lane < 16) ? wv[64 + lane] : 0u;
  sort128_u32(a0, b0, lane);
  unsigned T0k = (unsigned)__shfl((int)b0, 44);
  float T0f = u2f(T0k);

  // E: filter v >= T0, ballot-compact into candidate buffer
#pragma unroll
  for (int j = 0; j < 16; ++j) {
    bool pred = (v[j] >= T0f);
    unsigned long long m = __ballot(pred);
    int below = __popcll(m & ((1ull << lane) - 1ull));
    int cw = __popcll(m);
    int base = 0;
    if (lane == 0 && cw) base = atomicAdd(&cnt_s, cw);
    base = __shfl(base, 0);
    if (pred) {
      int pos = base + below;
      if (pos < 128) { ck[pos] = f2u(v[j]); ci[pos] = j * 256 + tid; }
    }
  }
  __syncthreads();
  const int cnt = cnt_s;

  if (cnt <= 128) {
    // F: exact top-20 via candidate sort (all waves redundant, wave 0 writes)
    unsigned long long k0 = (lane < cnt)
        ? (((unsigned long long)ck[lane] << 32) | (unsigned)(~ci[lane])) : 0ull;
    if (cnt <= 64) {
      k0 = sort64_u64(k0, lane);
      if (wid == 0 && lane >= 44) selm[63 - lane] = (int)(~(unsigned)k0);
    } else {
      unsigned long long k1 = (64 + lane < cnt)
          ? (((unsigned long long)ck[64 + lane] << 32) | (unsigned)(~ci[64 + lane])) : 0ull;
      sort128_u64(k0, k1, lane);
      if (wid == 0 && lane >= 44) selm[63 - lane] = (int)(~(unsigned)k1);
    }
  } else {
    // Fallback (ties/degenerate data): exact iterative extraction (round-4 algo)
    for (int it = 0; it < 20; ++it) {
      float bv = v[0]; int bj = 0;
#pragma unroll
      for (int j = 1; j < 16; ++j)
        if (v[j] > bv) { bv = v[j]; bj = j; }
      int bm = bj * 256 + tid;
#pragma unroll
      for (int off = 1; off < 64; off <<= 1) {
        float ov = __shfl_xor(bv, off);
        int om = __shfl_xor(bm, off);
        if (ov > bv || (ov == bv && om < bm)) { bv = ov; bm = om; }
      }
      if (lane == 0) { fcv[wid * 20 + it] = bv; fcm[wid * 20 + it] = bm; }
      if ((bm & 255) == tid) v[bm >> 8] = -3.0e38f;
    }
    __syncthreads();
    if (wid == 0) {
      float c0 = fcv[lane]; int m0 = fcm[lane];
      float c1 = (lane < 16) ? fcv[64 + lane] : -3.0e38f;
      int   m1 = (lane < 16) ? fcm[64 + lane] : 0x7fffffff;
      for (int it = 0; it < 20; ++it) {
        float bv; int bm, bs;
        if (c0 > c1 || (c0 == c1 && m0 < m1)) { bv = c0; bm = m0; bs = lane; }
        else { bv = c1; bm = m1; bs = 64 + lane; }
#pragma unroll
        for (int off = 1; off < 64; off <<= 1) {
          float ov = __shfl_xor(bv, off);
          int om = __shfl_xor(bm, off);
          int os = __shfl_xor(bs, off);
          if (ov > bv || (ov == bv && om < bm)) { bv = ov; bm = om; bs = os; }
        }
        if (lane == 0) selm[it] = bm;
        if (bs == lane) c0 = -3.0e38f;
        else if (bs == 64 + lane) c1 = -3.0e38f;
      }
    }
  }
  __syncthreads();

  // G: gather + leakyrelu + max over k; wave w handles neighbors 5w..5w+4
  for (int o = lane; o < O; o += 64) {
    float q = Q[(size_t)(bBase + n) * O + o];
    float best = -3.0e38f;
#pragma unroll
    for (int kk = 0; kk < 5; ++kk) {
      int s = selm[wid * 5 + kk];
      float t = P[(size_t)(bBase + s) * O + o] + q;
      t = t > 0.f ? t : 0.2f * t;
      best = fmaxf(best, t);
    }
    part[wid * 256 + o] = best;
  }
  __syncthreads();
  for (int o = tid; o < O; o += 256) {
    float b2 = fmaxf(fmaxf(part[o], part[256 + o]),
                     fmaxf(part[512 + o], part[768 + o]));
    Y[(size_t)(bBase + n) * ldy + o] = b2;
  }
}

// ---------------- final 128->1 dot ----------------
__global__ void final_dot_k(const float* __restrict__ h2, const float* __restrict__ w3,
                            const float* __restrict__ b3, float* __restrict__ out) {
  int gt = blockIdx.x * 256 + threadIdx.x;
  int row = gt >> 6, lane = gt & 63;
  float s = h2[(size_t)row * 128 + lane] * w3[lane] +
            h2[(size_t)row * 128 + 64 + lane] * w3[64 + lane];
#pragma unroll
  for (int off = 32; off > 0; off >>= 1) s += __shfl_down(s, off);
  if (lane == 0) out[row] = s + b3[0];
}

extern "C" void kernel_launch(void* const* d_in, const int* in_sizes, int n_in,
                              void* d_out, int out_size, void* d_ws, size_t ws_size,
                              hipStream_t stream) {
  const int B = 2, N = NPTS;
  const float* x = (const float*)d_in[0];
  const float* w[4]  = {(const float*)d_in[1], (const float*)d_in[6],
                        (const float*)d_in[11], (const float*)d_in[16]};
  const float* g[4]  = {(const float*)d_in[2], (const float*)d_in[7],
                        (const float*)d_in[12], (const float*)d_in[17]};
  const float* bt[4] = {(const float*)d_in[3], (const float*)d_in[8],
                        (const float*)d_in[13], (const float*)d_in[18]};
  const float* mm[4] = {(const float*)d_in[4], (const float*)d_in[9],
                        (const float*)d_in[14], (const float*)d_in[19]};
  const float* vv[4] = {(const float*)d_in[5], (const float*)d_in[10],
                        (const float*)d_in[15], (const float*)d_in[20]};
  const float* hw1 = (const float*)d_in[21]; const float* hb1 = (const float*)d_in[22];
  const float* hg1 = (const float*)d_in[23]; const float* hbt1 = (const float*)d_in[24];
  const float* hm1 = (const float*)d_in[25]; const float* hv1 = (const float*)d_in[26];
  const float* hw2 = (const float*)d_in[27]; const float* hb2 = (const float*)d_in[28];
  const float* hg2 = (const float*)d_in[29]; const float* hbt2 = (const float*)d_in[30];
  const float* hm2 = (const float*)d_in[31]; const float* hv2 = (const float*)d_in[32];
  const float* hw3 = (const float*)d_in[33]; const float* hb3 = (const float*)d_in[34];
  float* out = (float*)d_out;

  char* wsb = (char*)d_ws;
  size_t off = 0;
  auto alloc = [&](size_t nbytes) {
    char* p = wsb + off;
    off += (nbytes + 255) & ~(size_t)255;
    return p;
  };
  float* xc   = (float*)alloc((size_t)B * N * 512 * 4);
  float* P    = (float*)alloc((size_t)B * N * 256 * 4);
  float* Q    = (float*)alloc((size_t)B * N * 256 * 4);
  float* sq   = (float*)alloc((size_t)B * N * 4);
  float* wdf  = (float*)alloc(256 * 256 * 4);
  float* wqf  = (float*)alloc(256 * 256 * 4);
  float* c0   = (float*)alloc(256 * 4);
  float* hwf1 = (float*)alloc(256 * 512 * 4);
  float* cb1  = (float*)alloc(256 * 4);
  float* hwf2 = (float*)alloc(128 * 256 * 4);
  float* cb2  = (float*)alloc(128 * 4);
  float* D    = (float*)(wsb + off);
  size_t avail = (ws_size > off) ? (ws_size - off) : 0;
  int rows_tile = 4096;
  while ((size_t)rows_tile * N * 4 > avail && rows_tile > 64) rows_tile >>= 1;

  // dims = [(3,64), (64,64), (64,128), (128,256)]
  const int Cin[4]  = {3, 64, 64, 128};
  const int Oc[4]   = {64, 64, 128, 256};
  const int ioff[4] = {0, 0, 64, 128};
  const int ooff[4] = {0, 64, 128, 256};
  dim3 blk2(16, 16);

  for (int L = 0; L < 4; ++L) {
    const int C = Cin[L], O = Oc[L];
    const float* in = (L == 0) ? x : (xc + ioff[L]);
    const int lda = (L == 0) ? 3 : 512;

    fold_edge_k<<<dim3((O * C + 255) / 256), dim3(256), 0, stream>>>(
        w[L], g[L], bt[L], mm[L], vv[L], O, C, wdf, wqf, c0);
    sq_k<<<dim3((B * N + 255) / 256), dim3(256), 0, stream>>>(in, lda, C, sq, B * N);
    if (L == 0) {
      pq3_k<<<dim3(B * N * 64 / 256), dim3(256), 0, stream>>>(x, wdf, wqf, c0, P, Q);
    } else {
      gemm_nt<0><<<dim3(O / 64, B * N / 64), blk2, 0, stream>>>(
          in, lda, wdf, C, P, O, C, nullptr, nullptr, nullptr);
      gemm_nt<1><<<dim3(O / 64, B * N / 64), blk2, 0, stream>>>(
          in, lda, wqf, C, Q, O, C, nullptr, nullptr, c0);
    }
    for (int b = 0; b < B; ++b) {
      for (int r0 = 0; r0 < N; r0 += rows_tile) {
        if (L == 0) {
          dist3_k<<<dim3((unsigned)((size_t)rows_tile * N / 256)), dim3(256), 0, stream>>>(
              x + (size_t)b * N * 3, sq + b * N, D, r0);
        } else {
          gemm_nt<2><<<dim3(N / 64, rows_tile / 64), blk2, 0, stream>>>(
              in + ((size_t)b * N + r0) * lda, lda, in + (size_t)b * N * lda, lda,
              D, N, C, sq + b * N + r0, sq + b * N, nullptr);
        }
        topk_max_f32<<<dim3(rows_tile), dim3(256), 0, stream>>>(
            D, P, Q, xc + ooff[L], 512, O, b * N, r0);
      }
    }
  }

  fold_head_k<<<dim3((256 * 512 + 255) / 256), dim3(256), 0, stream>>>(
      hw1, hb1, hg1, hbt1, hm1, hv1, 256, 512, hwf1, cb1);
  fold_head_k<<<dim3((128 * 256 + 255) / 256), dim3(256), 0, stream>>>(
      hw2, hb2, hg2, hbt2, hm2, hv2, 128, 256, hwf2, cb2);

  float* h1 = P;
  float* h2 = Q;
  gemm_nt<3><<<dim3(256 / 64, B * N / 64), blk2, 0, stream>>>(
      xc, 512, hwf1, 512, h1, 256, 512, nullptr, nullptr, cb1);
  gemm_nt<3><<<dim3(128 / 64, B * N / 64), blk2, 0, stream>>>(
      h1, 256, hwf2, 256, h2, 128, 256, nullptr, nullptr, cb2);
  final_dot_k<<<dim3(B * N / 4), dim3(256), 0, stream>>>(h2, hw3, hb3, out);
}